// Round 1
// baseline (80.777 us; speedup 1.0000x reference)
//
#include <hip/hip_runtime.h>

// ResidualBlock2 (AdderNet): two adder-convs + BN + ReLU + residual.
// N=32, C=32, H=W=32, K=3. Pure-VALU compute (abs-diff conv, no MFMA).

#define NB 512          // conv grid blocks = N(32) * H-tiles(16), 2 rows/block
#define CONV_THREADS 256

// ---------------- quantize + transpose weights ----------------
// in : w[co][ci][kh][kw]  (9216 each)
// out: wqt[(ci*3+kh)*3+kw][co]  = wqt[r*32+co], r in [0,288)
__global__ __launch_bounds__(256) void quant_k(const float* __restrict__ w1,
                                               const float* __restrict__ w2,
                                               float* __restrict__ q1,
                                               float* __restrict__ q2) {
  int i = blockIdx.x * 256 + threadIdx.x;
  if (i >= 18432) return;
  const float* w = (i < 9216) ? w1 : w2;
  float* dst = (i < 9216) ? q1 : q2;
  int j = (i < 9216) ? i : i - 9216;
  int co = j / 288;
  int r = j - co * 288;
  const float scale = 2.5f / 127.f;
  float v = w[j] / scale;
  v = rintf(v);                       // round-half-even, matches jnp.round
  v = fminf(fmaxf(v, -127.f), 127.f);
  dst[r * 32 + co] = v * scale;
}

// ---------------- adder conv ----------------
// AFFINE=false: input used raw (conv1 on x).
// AFFINE=true : input element v -> relu(a[ci]*v + b[ci]) during staging (conv2).
// Block: 256 threads = 64 positions (2 rows x 32 cols) x 4 co-groups of 8.
// Writes raw conv output (negative abs-diff sum) and per-(co,block) float
// partial sum / sum-of-squares for the BN statistics (deterministic).
template <bool AFFINE>
__global__ __launch_bounds__(256) void adder_conv(
    const float* __restrict__ in,    // [32][32][32][32]
    const float* __restrict__ wqt,   // [288][32]
    const float* __restrict__ aff_a, // [32] or null
    const float* __restrict__ aff_b, // [32] or null
    float* __restrict__ out,         // [32][32][32][32]
    float* __restrict__ psum,        // [32][NB]
    float* __restrict__ psq) {       // [32][NB]
  __shared__ __align__(16) float xs[32][4][34];  // 17408 B  (rows h0-1..h0+2, cols -1..32)
  __shared__ __align__(16) float wl[288 * 32];   // 36864 B

  const int tid = threadIdx.x;
  const int blk = blockIdx.x;
  const int n  = blk >> 4;          // image
  const int h0 = (blk & 15) << 1;   // first output row of this block

  // stage weights (float4, coalesced; wqt is 16B aligned)
  {
    const float4* src = (const float4*)wqt;
    float4* dst = (float4*)wl;
    #pragma unroll
    for (int i = tid; i < 2304; i += 256) dst[i] = src[i];
  }
  // stage input tile with zero padding (and optional affine+relu)
  for (int i = tid; i < 32 * 4 * 34; i += 256) {
    int ci = i / 136;
    int rem = i - ci * 136;
    int r = rem / 34;
    int c = rem - r * 34;
    int h = h0 - 1 + r;
    int w = c - 1;
    float v = 0.f;
    if ((unsigned)h < 32u && (unsigned)w < 32u) {
      v = in[((n * 32 + ci) * 32 + h) * 32 + w];
      if (AFFINE) v = fmaxf(fmaf(aff_a[ci], v, aff_b[ci]), 0.f);
    }
    xs[ci][r][c] = v;
  }
  __syncthreads();

  const int pos = tid & 63;
  const int w = pos & 31;
  const int hl = pos >> 5;          // 0 or 1
  const int cg = tid >> 6;          // 0..3 -> co base cg*8

  float acc[8];
  #pragma unroll
  for (int j = 0; j < 8; ++j) acc[j] = 0.f;

  for (int ci = 0; ci < 32; ++ci) {
    #pragma unroll
    for (int kh = 0; kh < 3; ++kh) {
      const float x0 = xs[ci][hl + kh][w];
      const float x1 = xs[ci][hl + kh][w + 1];
      const float x2 = xs[ci][hl + kh][w + 2];
      #pragma unroll
      for (int kw = 0; kw < 3; ++kw) {
        const float xv = (kw == 0) ? x0 : ((kw == 1) ? x1 : x2);
        const float4* wp = (const float4*)&wl[((ci * 3 + kh) * 3 + kw) * 32 + cg * 8];
        const float4 wa = wp[0];
        const float4 wb4 = wp[1];
        acc[0] += fabsf(xv - wa.x);
        acc[1] += fabsf(xv - wa.y);
        acc[2] += fabsf(xv - wa.z);
        acc[3] += fabsf(xv - wa.w);
        acc[4] += fabsf(xv - wb4.x);
        acc[5] += fabsf(xv - wb4.y);
        acc[6] += fabsf(xv - wb4.z);
        acc[7] += fabsf(xv - wb4.w);
      }
    }
  }

  // write raw conv output (coalesced: 64 lanes -> 64 consecutive floats)
  const int h = h0 + hl;
  #pragma unroll
  for (int j = 0; j < 8; ++j) {
    const int co = cg * 8 + j;
    out[((n * 32 + co) * 32 + h) * 32 + w] = -acc[j];
  }
  // per-wave stats reduce (each wave owns co_base..co_base+7 for this block)
  #pragma unroll
  for (int j = 0; j < 8; ++j) {
    float o = -acc[j];
    float s = o;
    float q = o * o;
    #pragma unroll
    for (int d = 32; d; d >>= 1) {
      s += __shfl_xor(s, d);
      q += __shfl_xor(q, d);
    }
    if (pos == 0) {
      const int co = cg * 8 + j;
      psum[co * NB + blk] = s;
      psq[co * NB + blk] = q;
    }
  }
}

// ---------------- BN finalize: fold into per-channel affine ----------------
// a[c] = gamma/sqrt(var+eps);  b[c] = beta + wb - a*mu,  wb = mean|wq| per co.
__global__ __launch_bounds__(256) void fin_k(const float* __restrict__ ps,
                                             const float* __restrict__ pq,
                                             const float* __restrict__ wqt,
                                             const float* __restrict__ gamma,
                                             const float* __restrict__ beta,
                                             float* __restrict__ a,
                                             float* __restrict__ b) {
  const int c = blockIdx.x;
  const int tid = threadIdx.x;
  double s = 0.0, q = 0.0;
  for (int i = tid; i < NB; i += 256) {
    s += (double)ps[c * NB + i];
    q += (double)pq[c * NB + i];
  }
  float wbp = 0.f;
  for (int r = tid; r < 288; r += 256) wbp += fabsf(wqt[r * 32 + c]);
  #pragma unroll
  for (int d = 32; d; d >>= 1) {
    s += __shfl_xor(s, d);
    q += __shfl_xor(q, d);
    wbp += __shfl_xor(wbp, d);
  }
  __shared__ double sh[4], qh[4];
  __shared__ float wh[4];
  const int wv = tid >> 6;
  if ((tid & 63) == 0) { sh[wv] = s; qh[wv] = q; wh[wv] = wbp; }
  __syncthreads();
  if (tid == 0) {
    double S = 0, Q = 0;
    float W = 0;
    #pragma unroll
    for (int i = 0; i < 4; ++i) { S += sh[i]; Q += qh[i]; W += wh[i]; }
    const double M = 32768.0;
    const double mu = S / M;
    const double var = Q / M - mu * mu;
    const double inv = 1.0 / sqrt(var + 1e-5);
    const double g = (double)gamma[c];
    a[c] = (float)(g * inv);
    b[c] = (float)((double)beta[c] + (double)(W * (1.f / 288.f)) - g * inv * mu);
  }
}

// ---------------- final: relu(a2*o2 + b2 + x) ----------------
__global__ __launch_bounds__(256) void final_k(const float* __restrict__ o2,
                                               const float* __restrict__ x,
                                               const float* __restrict__ a,
                                               const float* __restrict__ b,
                                               float* __restrict__ out) {
  const int i = blockIdx.x * 256 + threadIdx.x;  // over 262144 float4s
  const int c = (i >> 8) & 31;                   // ((i*4) >> 10) & 31
  const float4 o = ((const float4*)o2)[i];
  const float4 xr = ((const float4*)x)[i];
  const float av = a[c], bv = b[c];
  float4 r;
  r.x = fmaxf(fmaf(av, o.x, bv) + xr.x, 0.f);
  r.y = fmaxf(fmaf(av, o.y, bv) + xr.y, 0.f);
  r.z = fmaxf(fmaf(av, o.z, bv) + xr.z, 0.f);
  r.w = fmaxf(fmaf(av, o.w, bv) + xr.w, 0.f);
  ((float4*)out)[i] = r;
}

extern "C" void kernel_launch(void* const* d_in, const int* in_sizes, int n_in,
                              void* d_out, int out_size, void* d_ws, size_t ws_size,
                              hipStream_t stream) {
  const float* x   = (const float*)d_in[0];
  const float* w1  = (const float*)d_in[1];
  const float* g1  = (const float*)d_in[2];
  const float* be1 = (const float*)d_in[3];
  const float* w2  = (const float*)d_in[4];
  const float* g2  = (const float*)d_in[5];
  const float* be2 = (const float*)d_in[6];
  float* ws = (float*)d_ws;

  // workspace layout (floats)
  float* WQ1 = ws;                 // 9216
  float* WQ2 = ws + 9216;          // 9216
  float* A1  = ws + 18432;         // 32
  float* B1  = ws + 18464;         // 32
  float* A2  = ws + 18496;         // 32
  float* B2  = ws + 18528;         // 32
  float* PS  = ws + 18560;         // 32*NB = 16384
  float* PQ  = PS + 16384;         // 16384
  float* O1  = ws + 51328;         // 1048576 (16B aligned)
  float* O2  = O1 + 1048576;       // 1048576
  float* out = (float*)d_out;

  quant_k<<<72, 256, 0, stream>>>(w1, w2, WQ1, WQ2);
  adder_conv<false><<<NB, CONV_THREADS, 0, stream>>>(x, WQ1, nullptr, nullptr, O1, PS, PQ);
  fin_k<<<32, 256, 0, stream>>>(PS, PQ, WQ1, g1, be1, A1, B1);
  adder_conv<true><<<NB, CONV_THREADS, 0, stream>>>(O1, WQ2, A1, B1, O2, PS, PQ);
  fin_k<<<32, 256, 0, stream>>>(PS, PQ, WQ2, g2, be2, A2, B2);
  final_k<<<1024, 256, 0, stream>>>(O2, x, A2, B2, out);
}